// Round 5
// baseline (1501.346 us; speedup 1.0000x reference)
//
#include <hip/hip_runtime.h>
#include <hip/hip_bf16.h>

#define DDIM 1024
#define HDIM 4096
#define NEXP 8
#define NROW 8192

typedef __attribute__((ext_vector_type(8))) short s16x8;
typedef __attribute__((ext_vector_type(4))) float f32x4;

using bf16 = __hip_bfloat16;

// ---------------------------------------------------------------- helpers
__device__ __forceinline__ void gload16(const bf16* g, bf16* lds) {
    __builtin_amdgcn_global_load_lds(
        (const __attribute__((address_space(1))) unsigned int*)g,
        (__attribute__((address_space(3))) unsigned int*)lds,
        16, 0, 0);
}

template <int N>
__device__ __forceinline__ void wait_vmcnt() {
    if constexpr (N == 6)      asm volatile("s_waitcnt vmcnt(6)" ::: "memory");
    else if constexpr (N == 3) asm volatile("s_waitcnt vmcnt(3)" ::: "memory");
    else                       asm volatile("s_waitcnt vmcnt(0)" ::: "memory");
}

// ---------------------------------------------------------------- x -> bf16
__global__ void cvt_x_kernel(const float* __restrict__ x, bf16* __restrict__ xb, int total4) {
    int i = blockIdx.x * 256 + threadIdx.x;
    if (i >= total4) return;
    float4 v = ((const float4*)x)[i];
    union { bf16 b[4]; uint2 u; } p;
    p.b[0] = __float2bfloat16(v.x);
    p.b[1] = __float2bfloat16(v.y);
    p.b[2] = __float2bfloat16(v.z);
    p.b[3] = __float2bfloat16(v.w);
    ((uint2*)xb)[i] = p.u;
}

// ------------------------------------------- fp32 [E][R][C] -> bf16 [E][C][R]
__global__ void transpose_cvt_kernel(const float* __restrict__ in, bf16* __restrict__ out,
                                     int R, int C) {
    __shared__ float tile[32][33];
    const size_t esz = (size_t)R * C;
    const float* src = in + (size_t)blockIdx.z * esz;
    bf16* dst = out + (size_t)blockIdx.z * esz;
    int c0 = blockIdx.x * 32, r0 = blockIdx.y * 32;
    int tx = threadIdx.x & 31, ty = threadIdx.x >> 5;   // 256 threads: 32 x 8
#pragma unroll
    for (int i = 0; i < 32; i += 8)
        tile[ty + i][tx] = src[(size_t)(r0 + ty + i) * C + (c0 + tx)];
    __syncthreads();
#pragma unroll
    for (int i = 0; i < 32; i += 8)
        dst[(size_t)(c0 + ty + i) * R + (r0 + tx)] = __float2bfloat16(tile[tx][ty + i]);
}

// ---------------------------------------------------------------- gate softmax
__global__ void gate_kernel(const float* __restrict__ x, const float* __restrict__ Wg,
                            const float* __restrict__ bg, float* __restrict__ wts) {
    int wave = threadIdx.x >> 6, lane = threadIdx.x & 63;
    int n = blockIdx.x * 4 + wave;
    const float* xr = x + (size_t)n * DDIM;
    float acc[NEXP] = {0.f, 0.f, 0.f, 0.f, 0.f, 0.f, 0.f, 0.f};
    for (int d = lane; d < DDIM; d += 64) {
        float xv = xr[d];
        const float* wr = Wg + (size_t)d * NEXP;
#pragma unroll
        for (int e = 0; e < NEXP; ++e) acc[e] += xv * wr[e];
    }
#pragma unroll
    for (int off = 32; off > 0; off >>= 1) {
#pragma unroll
        for (int e = 0; e < NEXP; ++e) acc[e] += __shfl_xor(acc[e], off, 64);
    }
    if (lane == 0) {
        float mx = -1e30f;
#pragma unroll
        for (int e = 0; e < NEXP; ++e) { acc[e] += bg[e]; mx = fmaxf(mx, acc[e]); }
        float s = 0.f;
#pragma unroll
        for (int e = 0; e < NEXP; ++e) { acc[e] = __expf(acc[e] - mx); s += acc[e]; }
        float inv = 1.0f / s;
#pragma unroll
        for (int e = 0; e < NEXP; ++e) wts[(size_t)n * NEXP + e] = acc[e] * inv;
    }
}

// ------------------------------------------- out[n,d] = sum_e w[n,e]*b2[e,d]
__global__ void out_init_kernel(const float* __restrict__ wts, const float* __restrict__ b2,
                                float* __restrict__ out) {
    size_t idx = (size_t)blockIdx.x * 256 + threadIdx.x;
    int d = (int)(idx & (DDIM - 1));
    size_t n = idx >> 10;
    const float* w = wts + n * NEXP;
    float s = 0.f;
#pragma unroll
    for (int e = 0; e < NEXP; ++e) s += w[e] * b2[(size_t)e * DDIM + d];
    out[idx] = s;
}

// ---------------------------------------------------------------- GEMM (m201 8-phase port)
// BM=256, BN (256 or 128), BK=64. 8 waves: WN=BN/64 in N, WM=8/WN in M.
// Wave tile: (256/WM) x 64. acc[4*MH][4], MH = (256/WM)/64.
// LDS: 2 bufs, each {A: [2ks][256][32], B: [2ks][BN][32]} bf16, ks-major so each
// K-half is a contiguous stage unit. Swizzle (0-conflict, round-3-verified):
// 16B chunk slot = kg ^ ((R>>1)&3), inverse applied to global src k-chunk.
// Schedule/iter (2 K-tiles t0,t1): BN=256: 8 phases, one half staged per phase,
// vmcnt(6) at ph4/ph8. BN=128: 4 phases, {A,B} half-pair per phase, vmcnt(3)
// at P2/P4. Never drains vmcnt to 0 in the loop. setprio(1) around MFMA.
// MODE 1: bf16 H = relu(acc+bias[col]); MODE 2: fp32 out += wts[row,e]*acc.
template <int BN, int MODE>
__global__ __launch_bounds__(512, 1) void gemm256(
    const bf16* __restrict__ A, const bf16* __restrict__ BT, void* __restrict__ Cout,
    const float* __restrict__ bias, const float* __restrict__ wts,
    int lda, int ldb, int ldc, int NT, int tilesM, int tilesN, int XGN, int expert) {
    constexpr int WN = BN / 64, WM = 8 / WN;
    constexpr int WROWS = 256 / WM;         // 128 or 64
    constexpr int MH = WROWS / 64;          // 2 or 1
    constexpr int HALFA = 256 * 32;         // elems per A K-half
    constexpr int HALFB = BN * 32;
    constexpr int ATOT = 2 * HALFA;
    constexpr int BUFE = ATOT + 2 * HALFB;
    constexpr int BR = BN / 128;            // B stage rounds per half (2 or 1)
    constexpr int VMC = (BN == 256) ? 6 : 3;
    __shared__ __align__(16) bf16 smem[2 * BUFE];

    const int tid = threadIdx.x;
    const int wave = tid >> 6, lane = tid & 63;
    const int wm = wave / WN, wn = wave % WN;
    const int r = lane & 15, kg = lane >> 4;

    // ---- 2-D XCD-aware tile mapping (round-3 FETCH-verified)
    const int xcd = blockIdx.x & 7, slot = blockIdx.x >> 3;
    const int XGM = 8 / XGN;
    const int rm = tilesM / XGM, rn = tilesN / XGN;
    const int g = slot >> 5, u = slot & 31;
    const int gpr = rn >> 3;
    const int gm = (g / gpr) * 4 + (u >> 3);
    const int gn = (g % gpr) * 8 + (u & 7);
    const int tm = (xcd / XGN) * rm + gm;
    const int tn = (xcd % XGN) * rn + gn;

    const bf16* gA = A + (size_t)tm * 256 * lda;
    const bf16* gB = BT + (size_t)tn * BN * ldb;

    f32x4 acc[4 * MH][4];
#pragma unroll
    for (int m = 0; m < 4 * MH; ++m)
#pragma unroll
        for (int n = 0; n < 4; ++n) acc[m][n] = (f32x4){0.f, 0.f, 0.f, 0.f};

    // ---- staging: one K-half of A or B (contiguous in LDS)
    auto stageA = [&](int t, int ks) {
        bf16* dst = smem + (t & 1) * BUFE + ks * HALFA;
#pragma unroll
        for (int j = 0; j < 2; ++j) {
            int c = j * 512 + tid;
            int R = c >> 2, kc = (c & 3) ^ ((R >> 1) & 3);
            gload16(gA + (size_t)R * lda + t * 64 + ks * 32 + kc * 8,
                    dst + (j * 512 + wave * 64) * 8);
        }
    };
    auto stageB = [&](int t, int ks) {
        bf16* dst = smem + (t & 1) * BUFE + ATOT + ks * HALFB;
#pragma unroll
        for (int j = 0; j < BR; ++j) {
            int c = j * 512 + tid;
            int R = c >> 2, kc = (c & 3) ^ ((R >> 1) & 3);
            gload16(gB + (size_t)R * ldb + t * 64 + ks * 32 + kc * 8,
                    dst + (j * 512 + wave * 64) * 8);
        }
    };

    // ---- fragment reads (swizzled)
    s16x8 a0[4], bb[4];
    auto ldA = [&](int buf, int ks, int mh) {
#pragma unroll
        for (int m = 0; m < 4; ++m) {
            int R = wm * WROWS + mh * 64 + m * 16 + r;
            a0[m] = *(const s16x8*)&smem[buf * BUFE + ks * HALFA + R * 32 +
                                         ((kg ^ ((R >> 1) & 3)) * 8)];
        }
    };
    auto ldB = [&](int buf, int ks) {
#pragma unroll
        for (int n = 0; n < 4; ++n) {
            int R = wn * 64 + n * 16 + r;
            bb[n] = *(const s16x8*)&smem[buf * BUFE + ATOT + ks * HALFB + R * 32 +
                                         ((kg ^ ((R >> 1) & 3)) * 8)];
        }
    };

    auto preMFMA = [&]() {
        __builtin_amdgcn_s_barrier();
        asm volatile("s_waitcnt lgkmcnt(0)" ::: "memory");
        __builtin_amdgcn_sched_barrier(0);
        __builtin_amdgcn_s_setprio(1);
    };
    auto postMFMA = [&](bool vm) {
        __builtin_amdgcn_s_setprio(0);
        if (vm) wait_vmcnt<VMC>();
        __builtin_amdgcn_s_barrier();
    };
    auto mfmaLo = [&]() {
#pragma unroll
        for (int m = 0; m < 4; ++m)
#pragma unroll
            for (int n = 0; n < 4; ++n)
                acc[m][n] = __builtin_amdgcn_mfma_f32_16x16x32_bf16(a0[m], bb[n], acc[m][n], 0, 0, 0);
    };
    auto mfmaHi = [&]() {
#pragma unroll
        for (int m = 0; m < 4; ++m)
#pragma unroll
            for (int n = 0; n < 4; ++n)
                acc[4 + m][n] = __builtin_amdgcn_mfma_f32_16x16x32_bf16(a0[m], bb[n], acc[4 + m][n], 0, 0, 0);
    };

    // ---- prologue
    if constexpr (MH == 2) {
        stageB(0, 0); stageA(0, 0); stageB(0, 1); stageA(0, 1);
        stageB(1, 0); stageA(1, 0); stageB(1, 1);   // A(1,1) staged at iter0 ph1
    } else {
        stageA(0, 0); stageB(0, 0); stageA(0, 1); stageB(0, 1);
        stageA(1, 0); stageB(1, 0);                 // {A,B}(1,1) staged at iter0 P1
    }
    wait_vmcnt<VMC>();
    __builtin_amdgcn_s_barrier();

    // ---- main loop: 2 K-tiles per iteration
    const int NI = NT / 2;
    for (int i = 0; i < NI; ++i) {
        const int t0 = 2 * i, t1 = t0 + 1;
        const bool g2 = (t0 + 2 < NT), g3 = (t1 + 2 < NT);
        if constexpr (MH == 2) {
            // ph1
            ldB(0, 0); ldA(0, 0, 0); stageA(t1, 1);
            preMFMA(); mfmaLo(); postMFMA(false);
            // ph2
            ldA(0, 0, 1); if (g2) stageB(t0 + 2, 0);
            preMFMA(); mfmaHi(); postMFMA(false);
            // ph3
            ldB(0, 1); ldA(0, 1, 0); if (g2) stageA(t0 + 2, 0);
            preMFMA(); mfmaLo(); postMFMA(false);
            // ph4
            ldA(0, 1, 1); if (g2) stageB(t0 + 2, 1);
            preMFMA(); mfmaHi(); postMFMA(true);
            // ph5
            ldB(1, 0); ldA(1, 0, 0); if (g2) stageA(t0 + 2, 1);
            preMFMA(); mfmaLo(); postMFMA(false);
            // ph6
            ldA(1, 0, 1); if (g3) stageB(t1 + 2, 0);
            preMFMA(); mfmaHi(); postMFMA(false);
            // ph7
            ldB(1, 1); ldA(1, 1, 0); if (g3) stageA(t1 + 2, 0);
            preMFMA(); mfmaLo(); postMFMA(false);
            // ph8
            ldA(1, 1, 1); if (g3) stageB(t1 + 2, 1);
            preMFMA(); mfmaHi(); postMFMA(true);
        } else {
            // P1
            ldB(0, 0); ldA(0, 0, 0); stageA(t1, 1); stageB(t1, 1);
            preMFMA(); mfmaLo(); postMFMA(false);
            // P2
            ldB(0, 1); ldA(0, 1, 0); if (g2) { stageA(t0 + 2, 0); stageB(t0 + 2, 0); }
            preMFMA(); mfmaLo(); postMFMA(true);
            // P3
            ldB(1, 0); ldA(1, 0, 0); if (g2) { stageA(t0 + 2, 1); stageB(t0 + 2, 1); }
            preMFMA(); mfmaLo(); postMFMA(false);
            // P4
            ldB(1, 1); ldA(1, 1, 0); if (g3) { stageA(t1 + 2, 0); stageB(t1 + 2, 0); }
            preMFMA(); mfmaLo(); postMFMA(true);
        }
    }

    // ---- epilogue. C/D: col = r, row = kg*4 + j within each 16x16 frag
    const size_t row0 = (size_t)tm * 256 + wm * WROWS;
    const int col0 = tn * BN + wn * 64;
    if (MODE == 1) {
        bf16* H = (bf16*)Cout;
#pragma unroll
        for (int n = 0; n < 4; ++n) {
            int cc = col0 + n * 16 + r;
            float bv = bias[cc];
#pragma unroll
            for (int mf = 0; mf < 4 * MH; ++mf) {
#pragma unroll
                for (int j = 0; j < 4; ++j) {
                    size_t rr = row0 + (mf >> 2) * 64 + (mf & 3) * 16 + kg * 4 + j;
                    float v = acc[mf][n][j] + bv;
                    v = v > 0.f ? v : 0.f;
                    H[rr * (size_t)ldc + cc] = __float2bfloat16(v);
                }
            }
        }
    } else {
        float* O = (float*)Cout;
#pragma unroll
        for (int mf = 0; mf < 4 * MH; ++mf) {
#pragma unroll
            for (int j = 0; j < 4; ++j) {
                size_t rr = row0 + (mf >> 2) * 64 + (mf & 3) * 16 + kg * 4 + j;
                float wv = wts[rr * NEXP + expert];
#pragma unroll
                for (int n = 0; n < 4; ++n) {
                    int cc = col0 + n * 16 + r;
                    O[rr * (size_t)ldc + cc] += wv * acc[mf][n][j];
                }
            }
        }
    }
}

// ---------------------------------------------------------------- launch
extern "C" void kernel_launch(void* const* d_in, const int* in_sizes, int n_in,
                              void* d_out, int out_size, void* d_ws, size_t ws_size,
                              hipStream_t stream) {
    const float* x  = (const float*)d_in[0];
    const float* Wg = (const float*)d_in[1];
    const float* bg = (const float*)d_in[2];
    const float* W1 = (const float*)d_in[3];
    const float* b1 = (const float*)d_in[4];
    const float* W2 = (const float*)d_in[5];
    const float* b2 = (const float*)d_in[6];
    float* out = (float*)d_out;

    char* ws = (char*)d_ws;
    bf16* xb   = (bf16*)(ws);                          // 16 MiB  [N][D]
    bf16* W1T  = (bf16*)(ws + (16ull << 20));          // 64 MiB  [E][H][D]
    bf16* W2T  = (bf16*)(ws + (80ull << 20));          // 64 MiB  [E][D][H]
    bf16* Hb   = (bf16*)(ws + (144ull << 20));         // 64 MiB  [N][H] (one expert)
    float* wts = (float*)(ws + (208ull << 20));        // 256 KiB [N][E]

    cvt_x_kernel<<<(NROW * DDIM / 4 + 255) / 256, 256, 0, stream>>>(x, xb, NROW * DDIM / 4);
    transpose_cvt_kernel<<<dim3(HDIM / 32, DDIM / 32, NEXP), 256, 0, stream>>>(W1, W1T, DDIM, HDIM);
    transpose_cvt_kernel<<<dim3(DDIM / 32, HDIM / 32, NEXP), 256, 0, stream>>>(W2, W2T, HDIM, DDIM);
    gate_kernel<<<NROW / 4, 256, 0, stream>>>(x, Wg, bg, wts);
    out_init_kernel<<<NROW * DDIM / 256, 256, 0, stream>>>(wts, b2, out);

    for (int e = 0; e < NEXP; ++e) {
        // GEMM1: M=8192 N=4096 K=1024 -> 32x16 tiles = 512 blocks; BN=256
        gemm256<256, 1><<<512, 512, 0, stream>>>(
            xb, W1T + (size_t)e * HDIM * DDIM, Hb, b1 + (size_t)e * HDIM, nullptr,
            DDIM, DDIM, HDIM, DDIM / 64, 32, 16, 2, e);
        // GEMM2: M=8192 N=1024 K=4096 -> 32x8 tiles = 256 blocks; BN=128
        gemm256<128, 2><<<256, 512, 0, stream>>>(
            Hb, W2T + (size_t)e * DDIM * HDIM, out, nullptr, wts,
            HDIM, HDIM, DDIM, HDIM / 64, 32, 8, 1, e);
    }
}

// Round 6
// 1395.651 us; speedup vs baseline: 1.0757x; 1.0757x over previous
//
#include <hip/hip_runtime.h>
#include <hip/hip_bf16.h>

#define DDIM 1024
#define HDIM 4096
#define NEXP 8
#define NROW 8192

typedef __attribute__((ext_vector_type(8))) short s16x8;
typedef __attribute__((ext_vector_type(4))) float f32x4;

using bf16 = __hip_bfloat16;

// ---------------------------------------------------------------- helpers
__device__ __forceinline__ void gload16(const bf16* g, bf16* lds) {
    __builtin_amdgcn_global_load_lds(
        (const __attribute__((address_space(1))) unsigned int*)g,
        (__attribute__((address_space(3))) unsigned int*)lds,
        16, 0, 0);
}

template <int N>
__device__ __forceinline__ void wait_vmcnt() {
    if constexpr (N == 6)      asm volatile("s_waitcnt vmcnt(6)" ::: "memory");
    else if constexpr (N == 3) asm volatile("s_waitcnt vmcnt(3)" ::: "memory");
    else                       asm volatile("s_waitcnt vmcnt(0)" ::: "memory");
}

// ---------------------------------------------------------------- x -> bf16
__global__ void cvt_x_kernel(const float* __restrict__ x, bf16* __restrict__ xb, int total4) {
    int i = blockIdx.x * 256 + threadIdx.x;
    if (i >= total4) return;
    float4 v = ((const float4*)x)[i];
    union { bf16 b[4]; uint2 u; } p;
    p.b[0] = __float2bfloat16(v.x);
    p.b[1] = __float2bfloat16(v.y);
    p.b[2] = __float2bfloat16(v.z);
    p.b[3] = __float2bfloat16(v.w);
    ((uint2*)xb)[i] = p.u;
}

// ------------------------------------------- fp32 [E][R][C] -> bf16 [E][C][R]
__global__ void transpose_cvt_kernel(const float* __restrict__ in, bf16* __restrict__ out,
                                     int R, int C) {
    __shared__ float tile[32][33];
    const size_t esz = (size_t)R * C;
    const float* src = in + (size_t)blockIdx.z * esz;
    bf16* dst = out + (size_t)blockIdx.z * esz;
    int c0 = blockIdx.x * 32, r0 = blockIdx.y * 32;
    int tx = threadIdx.x & 31, ty = threadIdx.x >> 5;   // 256 threads: 32 x 8
#pragma unroll
    for (int i = 0; i < 32; i += 8)
        tile[ty + i][tx] = src[(size_t)(r0 + ty + i) * C + (c0 + tx)];
    __syncthreads();
#pragma unroll
    for (int i = 0; i < 32; i += 8)
        dst[(size_t)(c0 + ty + i) * R + (r0 + tx)] = __float2bfloat16(tile[tx][ty + i]);
}

// ---------------------------------------------------------------- gate softmax
__global__ void gate_kernel(const float* __restrict__ x, const float* __restrict__ Wg,
                            const float* __restrict__ bg, float* __restrict__ wts) {
    int wave = threadIdx.x >> 6, lane = threadIdx.x & 63;
    int n = blockIdx.x * 4 + wave;
    const float* xr = x + (size_t)n * DDIM;
    float acc[NEXP] = {0.f, 0.f, 0.f, 0.f, 0.f, 0.f, 0.f, 0.f};
    for (int d = lane; d < DDIM; d += 64) {
        float xv = xr[d];
        const float* wr = Wg + (size_t)d * NEXP;
#pragma unroll
        for (int e = 0; e < NEXP; ++e) acc[e] += xv * wr[e];
    }
#pragma unroll
    for (int off = 32; off > 0; off >>= 1) {
#pragma unroll
        for (int e = 0; e < NEXP; ++e) acc[e] += __shfl_xor(acc[e], off, 64);
    }
    if (lane == 0) {
        float mx = -1e30f;
#pragma unroll
        for (int e = 0; e < NEXP; ++e) { acc[e] += bg[e]; mx = fmaxf(mx, acc[e]); }
        float s = 0.f;
#pragma unroll
        for (int e = 0; e < NEXP; ++e) { acc[e] = __expf(acc[e] - mx); s += acc[e]; }
        float inv = 1.0f / s;
#pragma unroll
        for (int e = 0; e < NEXP; ++e) wts[(size_t)n * NEXP + e] = acc[e] * inv;
    }
}

// ------------------------------------------- out[n,d] = sum_e w[n,e]*b2[e,d]
__global__ void out_init_kernel(const float* __restrict__ wts, const float* __restrict__ b2,
                                float* __restrict__ out) {
    size_t idx = (size_t)blockIdx.x * 256 + threadIdx.x;
    int d = (int)(idx & (DDIM - 1));
    size_t n = idx >> 10;
    const float* w = wts + n * NEXP;
    float s = 0.f;
#pragma unroll
    for (int e = 0; e < NEXP; ++e) s += w[e] * b2[(size_t)e * DDIM + d];
    out[idx] = s;
}

// ---------------------------------------------------------------- GEMM (8-phase, BK=64)
// BM=256, BN (256 or 128), BK=64. 8 waves: WN=BN/64 in N, WM=8/WN in M.
// LDS: 2 bufs {A: [2ks][256][32], B: [2ks][BN][32]}, ks-major halves.
// Swizzle (0-conflict): 16B slot = kg ^ ((R>>1)&3), inverse on global src.
// BN=256: 8 phases/2-K-tiles, one half per phase, vmcnt(6) at ph4/ph8.
// BN=128: 4 phases, {A,B} pair per phase, vmcnt(3) at P2/P4.
// MODE 1: bf16 H = relu(acc+bias), via LDS-buffered coalesced store
//         (scalar 2B stores caused 2.5x HBM write amplification, round-5 PMC).
// MODE 2: fp32 out += wts[row,e]*acc (RMW, line-adjacent stores).
template <int BN, int MODE>
__global__ __launch_bounds__(512, 1) void gemm256(
    const bf16* __restrict__ A, const bf16* __restrict__ BT, void* __restrict__ Cout,
    const float* __restrict__ bias, const float* __restrict__ wts,
    int lda, int ldb, int ldc, int NT, int tilesM, int tilesN, int XGN, int expert) {
    constexpr int WN = BN / 64, WM = 8 / WN;
    constexpr int WROWS = 256 / WM;         // 128 or 64
    constexpr int MH = WROWS / 64;          // 2 or 1
    constexpr int HALFA = 256 * 32;
    constexpr int HALFB = BN * 32;
    constexpr int ATOT = 2 * HALFA;
    constexpr int BUFE = ATOT + 2 * HALFB;
    constexpr int BR = BN / 128;
    constexpr int VMC = (BN == 256) ? 6 : 3;
    __shared__ __align__(16) bf16 smem[2 * BUFE];

    const int tid = threadIdx.x;
    const int wave = tid >> 6, lane = tid & 63;
    const int wm = wave / WN, wn = wave % WN;
    const int r = lane & 15, kg = lane >> 4;

    // ---- 2-D XCD-aware tile mapping (round-3 FETCH-verified)
    const int xcd = blockIdx.x & 7, slot = blockIdx.x >> 3;
    const int XGM = 8 / XGN;
    const int rm = tilesM / XGM, rn = tilesN / XGN;
    const int g = slot >> 5, u = slot & 31;
    const int gpr = rn >> 3;
    const int gm = (g / gpr) * 4 + (u >> 3);
    const int gn = (g % gpr) * 8 + (u & 7);
    const int tm = (xcd / XGN) * rm + gm;
    const int tn = (xcd % XGN) * rn + gn;

    const bf16* gA = A + (size_t)tm * 256 * lda;
    const bf16* gB = BT + (size_t)tn * BN * ldb;

    f32x4 acc[4 * MH][4];
#pragma unroll
    for (int m = 0; m < 4 * MH; ++m)
#pragma unroll
        for (int n = 0; n < 4; ++n) acc[m][n] = (f32x4){0.f, 0.f, 0.f, 0.f};

    auto stageA = [&](int t, int ks) {
        bf16* dst = smem + (t & 1) * BUFE + ks * HALFA;
#pragma unroll
        for (int j = 0; j < 2; ++j) {
            int c = j * 512 + tid;
            int R = c >> 2, kc = (c & 3) ^ ((R >> 1) & 3);
            gload16(gA + (size_t)R * lda + t * 64 + ks * 32 + kc * 8,
                    dst + (j * 512 + wave * 64) * 8);
        }
    };
    auto stageB = [&](int t, int ks) {
        bf16* dst = smem + (t & 1) * BUFE + ATOT + ks * HALFB;
#pragma unroll
        for (int j = 0; j < BR; ++j) {
            int c = j * 512 + tid;
            int R = c >> 2, kc = (c & 3) ^ ((R >> 1) & 3);
            gload16(gB + (size_t)R * ldb + t * 64 + ks * 32 + kc * 8,
                    dst + (j * 512 + wave * 64) * 8);
        }
    };

    s16x8 a0[4], bb[4];
    auto ldA = [&](int buf, int ks, int mh) {
#pragma unroll
        for (int m = 0; m < 4; ++m) {
            int R = wm * WROWS + mh * 64 + m * 16 + r;
            a0[m] = *(const s16x8*)&smem[buf * BUFE + ks * HALFA + R * 32 +
                                         ((kg ^ ((R >> 1) & 3)) * 8)];
        }
    };
    auto ldB = [&](int buf, int ks) {
#pragma unroll
        for (int n = 0; n < 4; ++n) {
            int R = wn * 64 + n * 16 + r;
            bb[n] = *(const s16x8*)&smem[buf * BUFE + ATOT + ks * HALFB + R * 32 +
                                         ((kg ^ ((R >> 1) & 3)) * 8)];
        }
    };

    auto preMFMA = [&]() {
        __builtin_amdgcn_s_barrier();
        asm volatile("s_waitcnt lgkmcnt(0)" ::: "memory");
        __builtin_amdgcn_sched_barrier(0);
        __builtin_amdgcn_s_setprio(1);
    };
    auto postMFMA = [&](bool vm) {
        __builtin_amdgcn_s_setprio(0);
        if (vm) wait_vmcnt<VMC>();
        __builtin_amdgcn_s_barrier();
    };
    auto mfmaLo = [&]() {
#pragma unroll
        for (int m = 0; m < 4; ++m)
#pragma unroll
            for (int n = 0; n < 4; ++n)
                acc[m][n] = __builtin_amdgcn_mfma_f32_16x16x32_bf16(a0[m], bb[n], acc[m][n], 0, 0, 0);
    };
    auto mfmaHi = [&]() {
#pragma unroll
        for (int m = 0; m < 4; ++m)
#pragma unroll
            for (int n = 0; n < 4; ++n)
                acc[4 + m][n] = __builtin_amdgcn_mfma_f32_16x16x32_bf16(a0[m], bb[n], acc[4 + m][n], 0, 0, 0);
    };

    // ---- prologue
    if constexpr (MH == 2) {
        stageB(0, 0); stageA(0, 0); stageB(0, 1); stageA(0, 1);
        stageB(1, 0); stageA(1, 0); stageB(1, 1);   // A(1,1) staged at iter0 ph1
    } else {
        stageA(0, 0); stageB(0, 0); stageA(0, 1); stageB(0, 1);
        stageA(1, 0); stageB(1, 0);                 // {A,B}(1,1) staged at iter0 P1
    }
    wait_vmcnt<VMC>();
    __builtin_amdgcn_s_barrier();

    // ---- main loop: 2 K-tiles per iteration
    const int NI = NT / 2;
    for (int i = 0; i < NI; ++i) {
        const int t0 = 2 * i, t1 = t0 + 1;
        const bool g2 = (t0 + 2 < NT), g3 = (t1 + 2 < NT);
        if constexpr (MH == 2) {
            ldB(0, 0); ldA(0, 0, 0); stageA(t1, 1);
            preMFMA(); mfmaLo(); postMFMA(false);
            ldA(0, 0, 1); if (g2) stageB(t0 + 2, 0);
            preMFMA(); mfmaHi(); postMFMA(false);
            ldB(0, 1); ldA(0, 1, 0); if (g2) stageA(t0 + 2, 0);
            preMFMA(); mfmaLo(); postMFMA(false);
            ldA(0, 1, 1); if (g2) stageB(t0 + 2, 1);
            preMFMA(); mfmaHi(); postMFMA(true);
            ldB(1, 0); ldA(1, 0, 0); if (g2) stageA(t0 + 2, 1);
            preMFMA(); mfmaLo(); postMFMA(false);
            ldA(1, 0, 1); if (g3) stageB(t1 + 2, 0);
            preMFMA(); mfmaHi(); postMFMA(false);
            ldB(1, 1); ldA(1, 1, 0); if (g3) stageA(t1 + 2, 0);
            preMFMA(); mfmaLo(); postMFMA(false);
            ldA(1, 1, 1); if (g3) stageB(t1 + 2, 1);
            preMFMA(); mfmaHi(); postMFMA(true);
        } else {
            ldB(0, 0); ldA(0, 0, 0); stageA(t1, 1); stageB(t1, 1);
            preMFMA(); mfmaLo(); postMFMA(false);
            ldB(0, 1); ldA(0, 1, 0); if (g2) { stageA(t0 + 2, 0); stageB(t0 + 2, 0); }
            preMFMA(); mfmaLo(); postMFMA(true);
            ldB(1, 0); ldA(1, 0, 0); if (g2) { stageA(t0 + 2, 1); stageB(t0 + 2, 1); }
            preMFMA(); mfmaLo(); postMFMA(false);
            ldB(1, 1); ldA(1, 1, 0); if (g3) { stageA(t1 + 2, 0); stageB(t1 + 2, 0); }
            preMFMA(); mfmaLo(); postMFMA(true);
        }
    }

    // ---- epilogue. acc C/D: col = r, row = kg*4 + j within each 16x16 frag
    if (MODE == 1) {
        // LDS-buffered coalesced store: smem is dead (loop ends with barrier)
        // and 2*BUFE elems == 256*256 exactly for BN=256.
        bf16* hs = smem;
        const int col0 = tn * BN + wn * 64;
#pragma unroll
        for (int n = 0; n < 4; ++n) {
            float bv = bias[col0 + n * 16 + r];
            int cl = wn * 64 + n * 16 + r;
#pragma unroll
            for (int mf = 0; mf < 4 * MH; ++mf) {
#pragma unroll
                for (int j = 0; j < 4; ++j) {
                    int rl = wm * WROWS + (mf >> 2) * 64 + (mf & 3) * 16 + kg * 4 + j;
                    float v = acc[mf][n][j] + bv;
                    v = v > 0.f ? v : 0.f;
                    hs[rl * 256 + cl] = __float2bfloat16(v);
                }
            }
        }
        __builtin_amdgcn_s_barrier();
        asm volatile("s_waitcnt lgkmcnt(0)" ::: "memory");
        bf16* H = (bf16*)Cout;
        const size_t rbase = (size_t)tm * 256;
        const int cbase = tn * BN;
        // wave w streams rows [w*32, w*32+32): 2 full rows (512B each) per inst
#pragma unroll
        for (int i2 = 0; i2 < 16; ++i2) {
            int rl = wave * 32 + i2 * 2 + (lane >> 5);
            int c8 = (lane & 31) * 8;
            s16x8 v = *(const s16x8*)&hs[rl * 256 + c8];
            *(s16x8*)&H[(rbase + rl) * (size_t)ldc + cbase + c8] = v;
        }
    } else {
        float* O = (float*)Cout;
        const size_t row0 = (size_t)tm * 256 + wm * WROWS;
        const int col0 = tn * BN + wn * 64;
#pragma unroll
        for (int mf = 0; mf < 4 * MH; ++mf) {
#pragma unroll
            for (int j = 0; j < 4; ++j) {
                size_t rr = row0 + (mf >> 2) * 64 + (mf & 3) * 16 + kg * 4 + j;
                float wv = wts[rr * NEXP + expert];
#pragma unroll
                for (int n = 0; n < 4; ++n) {
                    int cc = col0 + n * 16 + r;
                    O[rr * (size_t)ldc + cc] += wv * acc[mf][n][j];
                }
            }
        }
    }
}

// ---------------------------------------------------------------- launch
extern "C" void kernel_launch(void* const* d_in, const int* in_sizes, int n_in,
                              void* d_out, int out_size, void* d_ws, size_t ws_size,
                              hipStream_t stream) {
    const float* x  = (const float*)d_in[0];
    const float* Wg = (const float*)d_in[1];
    const float* bg = (const float*)d_in[2];
    const float* W1 = (const float*)d_in[3];
    const float* b1 = (const float*)d_in[4];
    const float* W2 = (const float*)d_in[5];
    const float* b2 = (const float*)d_in[6];
    float* out = (float*)d_out;

    char* ws = (char*)d_ws;
    bf16* xb   = (bf16*)(ws);                          // 16 MiB  [N][D]
    bf16* W1T  = (bf16*)(ws + (16ull << 20));          // 64 MiB  [E][H][D]
    bf16* W2T  = (bf16*)(ws + (80ull << 20));          // 64 MiB  [E][D][H]
    bf16* Hb   = (bf16*)(ws + (144ull << 20));         // 64 MiB  [N][H] (one expert)
    float* wts = (float*)(ws + (208ull << 20));        // 256 KiB [N][E]

    cvt_x_kernel<<<(NROW * DDIM / 4 + 255) / 256, 256, 0, stream>>>(x, xb, NROW * DDIM / 4);
    transpose_cvt_kernel<<<dim3(HDIM / 32, DDIM / 32, NEXP), 256, 0, stream>>>(W1, W1T, DDIM, HDIM);
    transpose_cvt_kernel<<<dim3(DDIM / 32, HDIM / 32, NEXP), 256, 0, stream>>>(W2, W2T, HDIM, DDIM);
    gate_kernel<<<NROW / 4, 256, 0, stream>>>(x, Wg, bg, wts);
    out_init_kernel<<<NROW * DDIM / 256, 256, 0, stream>>>(wts, b2, out);

    for (int e = 0; e < NEXP; ++e) {
        // GEMM1: M=8192 N=4096 K=1024 -> 32x16 tiles = 512 blocks; BN=256
        gemm256<256, 1><<<512, 512, 0, stream>>>(
            xb, W1T + (size_t)e * HDIM * DDIM, Hb, b1 + (size_t)e * HDIM, nullptr,
            DDIM, DDIM, HDIM, DDIM / 64, 32, 16, 2, e);
        // GEMM2: M=8192 N=1024 K=4096 -> 32x8 tiles = 256 blocks; BN=128
        gemm256<128, 2><<<256, 512, 0, stream>>>(
            Hb, W2T + (size_t)e * DDIM * HDIM, out, nullptr, wts,
            HDIM, HDIM, DDIM, HDIM / 64, 32, 8, 1, e);
    }
}

// Round 7
// 1336.642 us; speedup vs baseline: 1.1232x; 1.0441x over previous
//
#include <hip/hip_runtime.h>
#include <hip/hip_bf16.h>

#define DDIM 1024
#define HDIM 4096
#define NEXP 8
#define NROW 8192
#define KPAIR 8192   // 2 experts * HDIM

typedef __attribute__((ext_vector_type(8))) short s16x8;
typedef __attribute__((ext_vector_type(4))) float f32x4;

using bf16 = __hip_bfloat16;

// ---------------------------------------------------------------- helpers
__device__ __forceinline__ void gload16(const bf16* g, bf16* lds) {
    __builtin_amdgcn_global_load_lds(
        (const __attribute__((address_space(1))) unsigned int*)g,
        (__attribute__((address_space(3))) unsigned int*)lds,
        16, 0, 0);
}

template <int N>
__device__ __forceinline__ void wait_vmcnt() {
    if constexpr (N == 6)      asm volatile("s_waitcnt vmcnt(6)" ::: "memory");
    else if constexpr (N == 3) asm volatile("s_waitcnt vmcnt(3)" ::: "memory");
    else                       asm volatile("s_waitcnt vmcnt(0)" ::: "memory");
}

// ---------------------------------------------------------------- x -> bf16
__global__ void cvt_x_kernel(const float* __restrict__ x, bf16* __restrict__ xb, int total4) {
    int i = blockIdx.x * 256 + threadIdx.x;
    if (i >= total4) return;
    float4 v = ((const float4*)x)[i];
    union { bf16 b[4]; uint2 u; } p;
    p.b[0] = __float2bfloat16(v.x);
    p.b[1] = __float2bfloat16(v.y);
    p.b[2] = __float2bfloat16(v.z);
    p.b[3] = __float2bfloat16(v.w);
    ((uint2*)xb)[i] = p.u;
}

// ------------------------------ fp32 [R][C] -> bf16 [C][ldo] (dst pre-offset)
__global__ void transpose_cvt_kernel(const float* __restrict__ src, bf16* __restrict__ dst,
                                     int R, int C, int ldo) {
    __shared__ float tile[32][33];
    int c0 = blockIdx.x * 32, r0 = blockIdx.y * 32;
    int tx = threadIdx.x & 31, ty = threadIdx.x >> 5;   // 256 threads: 32 x 8
#pragma unroll
    for (int i = 0; i < 32; i += 8)
        tile[ty + i][tx] = src[(size_t)(r0 + ty + i) * C + (c0 + tx)];
    __syncthreads();
#pragma unroll
    for (int i = 0; i < 32; i += 8)
        dst[(size_t)(c0 + ty + i) * ldo + (r0 + tx)] = __float2bfloat16(tile[tx][ty + i]);
}

// ---------------------------------------------------------------- gate softmax
__global__ void gate_kernel(const float* __restrict__ x, const float* __restrict__ Wg,
                            const float* __restrict__ bg, float* __restrict__ wts) {
    int wave = threadIdx.x >> 6, lane = threadIdx.x & 63;
    int n = blockIdx.x * 4 + wave;
    const float* xr = x + (size_t)n * DDIM;
    float acc[NEXP] = {0.f, 0.f, 0.f, 0.f, 0.f, 0.f, 0.f, 0.f};
    for (int d = lane; d < DDIM; d += 64) {
        float xv = xr[d];
        const float* wr = Wg + (size_t)d * NEXP;
#pragma unroll
        for (int e = 0; e < NEXP; ++e) acc[e] += xv * wr[e];
    }
#pragma unroll
    for (int off = 32; off > 0; off >>= 1) {
#pragma unroll
        for (int e = 0; e < NEXP; ++e) acc[e] += __shfl_xor(acc[e], off, 64);
    }
    if (lane == 0) {
        float mx = -1e30f;
#pragma unroll
        for (int e = 0; e < NEXP; ++e) { acc[e] += bg[e]; mx = fmaxf(mx, acc[e]); }
        float s = 0.f;
#pragma unroll
        for (int e = 0; e < NEXP; ++e) { acc[e] = __expf(acc[e] - mx); s += acc[e]; }
        float inv = 1.0f / s;
#pragma unroll
        for (int e = 0; e < NEXP; ++e) wts[(size_t)n * NEXP + e] = acc[e] * inv;
    }
}

// ------------------------------------------- out[n,d] = sum_e w[n,e]*b2[e,d]
__global__ void out_init_kernel(const float* __restrict__ wts, const float* __restrict__ b2,
                                float* __restrict__ out) {
    size_t idx = (size_t)blockIdx.x * 256 + threadIdx.x;
    int d = (int)(idx & (DDIM - 1));
    size_t n = idx >> 10;
    const float* w = wts + n * NEXP;
    float s = 0.f;
#pragma unroll
    for (int e = 0; e < NEXP; ++e) s += w[e] * b2[(size_t)e * DDIM + d];
    out[idx] = s;
}

// ---------------------------------------------------------------- GEMM1 (8-phase, BK=64)
// BM=256 x BN=256, 8 waves 2(M)x4(N), wave-tile 128x64.
// Epilogue: Hs = wts[row,e] * relu(acc + b1[col]) -> bf16, LDS-buffered
// coalesced store (round-6-verified: kills write amplification).
__global__ __launch_bounds__(512, 1) void gemm1(
    const bf16* __restrict__ A, const bf16* __restrict__ BT, bf16* __restrict__ Cout,
    const float* __restrict__ bias, const float* __restrict__ wts,
    int lda, int ldb, int ldc, int NT, int tilesM, int tilesN, int XGN, int expert) {
    constexpr int WROWS = 128;
    constexpr int HALFA = 256 * 32;
    constexpr int HALFB = 256 * 32;
    constexpr int ATOT = 2 * HALFA;
    constexpr int BUFE = ATOT + 2 * HALFB;  // 32768 elems
    __shared__ __align__(16) bf16 smem[2 * BUFE];

    const int tid = threadIdx.x;
    const int wave = tid >> 6, lane = tid & 63;
    const int wm = wave >> 2, wn = wave & 3;
    const int r = lane & 15, kg = lane >> 4;

    // ---- 2-D XCD-aware tile mapping (round-3 FETCH-verified)
    const int xcd = blockIdx.x & 7, slot = blockIdx.x >> 3;
    const int XGM = 8 / XGN;
    const int rm = tilesM / XGM, rn = tilesN / XGN;
    const int g = slot >> 5, u = slot & 31;
    const int gpr = rn >> 3;
    const int gm = (g / gpr) * 4 + (u >> 3);
    const int gn = (g % gpr) * 8 + (u & 7);
    const int tm = (xcd / XGN) * rm + gm;
    const int tn = (xcd % XGN) * rn + gn;

    const bf16* gA = A + (size_t)tm * 256 * lda;
    const bf16* gB = BT + (size_t)tn * 256 * ldb;

    f32x4 acc[8][4];
#pragma unroll
    for (int m = 0; m < 8; ++m)
#pragma unroll
        for (int n = 0; n < 4; ++n) acc[m][n] = (f32x4){0.f, 0.f, 0.f, 0.f};

    auto stageA = [&](int t, int ks) {
        bf16* dst = smem + (t & 1) * BUFE + ks * HALFA;
#pragma unroll
        for (int j = 0; j < 2; ++j) {
            int c = j * 512 + tid;
            int R = c >> 2, kc = (c & 3) ^ ((R >> 1) & 3);
            gload16(gA + (size_t)R * lda + t * 64 + ks * 32 + kc * 8,
                    dst + (j * 512 + wave * 64) * 8);
        }
    };
    auto stageB = [&](int t, int ks) {
        bf16* dst = smem + (t & 1) * BUFE + ATOT + ks * HALFB;
#pragma unroll
        for (int j = 0; j < 2; ++j) {
            int c = j * 512 + tid;
            int R = c >> 2, kc = (c & 3) ^ ((R >> 1) & 3);
            gload16(gB + (size_t)R * ldb + t * 64 + ks * 32 + kc * 8,
                    dst + (j * 512 + wave * 64) * 8);
        }
    };

    s16x8 a0[4], bb[4];
    auto ldA = [&](int buf, int ks, int mh) {
#pragma unroll
        for (int m = 0; m < 4; ++m) {
            int R = wm * WROWS + mh * 64 + m * 16 + r;
            a0[m] = *(const s16x8*)&smem[buf * BUFE + ks * HALFA + R * 32 +
                                         ((kg ^ ((R >> 1) & 3)) * 8)];
        }
    };
    auto ldB = [&](int buf, int ks) {
#pragma unroll
        for (int n = 0; n < 4; ++n) {
            int R = wn * 64 + n * 16 + r;
            bb[n] = *(const s16x8*)&smem[buf * BUFE + ATOT + ks * HALFB + R * 32 +
                                         ((kg ^ ((R >> 1) & 3)) * 8)];
        }
    };

    auto preMFMA = [&]() {
        __builtin_amdgcn_s_barrier();
        asm volatile("s_waitcnt lgkmcnt(0)" ::: "memory");
        __builtin_amdgcn_sched_barrier(0);
        __builtin_amdgcn_s_setprio(1);
    };
    auto postMFMA = [&](bool vm) {
        __builtin_amdgcn_s_setprio(0);
        if (vm) wait_vmcnt<6>();
        __builtin_amdgcn_s_barrier();
    };
    auto mfmaLo = [&]() {
#pragma unroll
        for (int m = 0; m < 4; ++m)
#pragma unroll
            for (int n = 0; n < 4; ++n)
                acc[m][n] = __builtin_amdgcn_mfma_f32_16x16x32_bf16(a0[m], bb[n], acc[m][n], 0, 0, 0);
    };
    auto mfmaHi = [&]() {
#pragma unroll
        for (int m = 0; m < 4; ++m)
#pragma unroll
            for (int n = 0; n < 4; ++n)
                acc[4 + m][n] = __builtin_amdgcn_mfma_f32_16x16x32_bf16(a0[m], bb[n], acc[4 + m][n], 0, 0, 0);
    };

    // prologue
    stageB(0, 0); stageA(0, 0); stageB(0, 1); stageA(0, 1);
    stageB(1, 0); stageA(1, 0); stageB(1, 1);   // A(1,1) staged at iter0 ph1
    wait_vmcnt<6>();
    __builtin_amdgcn_s_barrier();

    const int NI = NT / 2;
    for (int i = 0; i < NI; ++i) {
        const int t0 = 2 * i, t1 = t0 + 1;
        const bool g2 = (t0 + 2 < NT), g3 = (t1 + 2 < NT);
        ldB(0, 0); ldA(0, 0, 0); stageA(t1, 1);
        preMFMA(); mfmaLo(); postMFMA(false);
        ldA(0, 0, 1); if (g2) stageB(t0 + 2, 0);
        preMFMA(); mfmaHi(); postMFMA(false);
        ldB(0, 1); ldA(0, 1, 0); if (g2) stageA(t0 + 2, 0);
        preMFMA(); mfmaLo(); postMFMA(false);
        ldA(0, 1, 1); if (g2) stageB(t0 + 2, 1);
        preMFMA(); mfmaHi(); postMFMA(true);
        ldB(1, 0); ldA(1, 0, 0); if (g2) stageA(t0 + 2, 1);
        preMFMA(); mfmaLo(); postMFMA(false);
        ldA(1, 0, 1); if (g3) stageB(t1 + 2, 0);
        preMFMA(); mfmaHi(); postMFMA(false);
        ldB(1, 1); ldA(1, 1, 0); if (g3) stageA(t1 + 2, 0);
        preMFMA(); mfmaLo(); postMFMA(false);
        ldA(1, 1, 1); if (g3) stageB(t1 + 2, 1);
        preMFMA(); mfmaHi(); postMFMA(true);
    }

    // ---- epilogue: Hs = w * relu(acc + bias), LDS-buffered coalesced store
    bf16* hs = smem;                         // 65536 elems == 256*256
    const int col0 = tn * 256 + wn * 64;
#pragma unroll
    for (int n = 0; n < 4; ++n) {
        float bv = bias[col0 + n * 16 + r];
        int cl = wn * 64 + n * 16 + r;
#pragma unroll
        for (int mf = 0; mf < 8; ++mf) {
#pragma unroll
            for (int j = 0; j < 4; ++j) {
                int rl = wm * WROWS + (mf >> 2) * 64 + (mf & 3) * 16 + kg * 4 + j;
                float wv = wts[((size_t)tm * 256 + rl) * NEXP + expert];
                float v = acc[mf][n][j] + bv;
                v = v > 0.f ? v : 0.f;
                hs[rl * 256 + cl] = __float2bfloat16(wv * v);
            }
        }
    }
    __builtin_amdgcn_s_barrier();
    asm volatile("s_waitcnt lgkmcnt(0)" ::: "memory");
    const size_t rbase = (size_t)tm * 256;
    const int cbase = tn * 256;
#pragma unroll
    for (int i2 = 0; i2 < 16; ++i2) {
        int rl = wave * 32 + i2 * 2 + (lane >> 5);
        int c8 = (lane & 31) * 8;
        s16x8 v = *(const s16x8*)&hs[rl * 256 + c8];
        *(s16x8*)&Cout[(rbase + rl) * (size_t)ldc + cbase + c8] = v;
    }
}

// ---------------------------------------------------------------- GEMM2 (expert-pair, K=8192)
// BM=256 x BN=128, BK=64, ring-3 LDS. 8 waves = 2(M) x 2(N) x 2(K-split):
// wave-tile 128x64 over one 32-k half -> 12 ds_reads / 32 MFMA (0.375).
// Cross-wave acc reduce via LDS, then fp32 RMW into out (w already folded).
__global__ __launch_bounds__(512, 1) void gemm2pair(
    const bf16* __restrict__ A, const bf16* __restrict__ BT, float* __restrict__ O,
    int lda, int ldb, int ldc, int NT, int tilesM, int tilesN, int XGN) {
    constexpr int HALFA = 256 * 32;          // 8192 elems
    constexpr int HALFB = 128 * 32;          // 4096 elems
    constexpr int ATOT = 2 * HALFA;
    constexpr int BUFE = ATOT + 2 * HALFB;   // 24576 elems
    __shared__ __align__(16) bf16 smem[3 * BUFE];   // 144 KiB

    const int tid = threadIdx.x;
    const int wave = tid >> 6, lane = tid & 63;
    const int ksw = wave & 1, wn = (wave >> 1) & 1, wm = wave >> 2;
    const int r = lane & 15, kg = lane >> 4;

    // ---- 2-D XCD-aware tile mapping (round-3 FETCH-verified)
    const int xcd = blockIdx.x & 7, slot = blockIdx.x >> 3;
    const int XGM = 8 / XGN;
    const int rm = tilesM / XGM, rn = tilesN / XGN;
    const int g = slot >> 5, u = slot & 31;
    const int gpr = rn >> 3;
    const int gm = (g / gpr) * 4 + (u >> 3);
    const int gn = (g % gpr) * 8 + (u & 7);
    const int tm = (xcd / XGN) * rm + gm;
    const int tn = (xcd % XGN) * rn + gn;

    const bf16* gA = A + (size_t)tm * 256 * lda;
    const bf16* gB = BT + (size_t)tn * 128 * ldb;

    f32x4 acc[8][4];
#pragma unroll
    for (int m = 0; m < 8; ++m)
#pragma unroll
        for (int n = 0; n < 4; ++n) acc[m][n] = (f32x4){0.f, 0.f, 0.f, 0.f};

    auto stageA = [&](int t, int ks) {
        bf16* dst = smem + (t % 3) * BUFE + ks * HALFA;
#pragma unroll
        for (int j = 0; j < 2; ++j) {
            int c = j * 512 + tid;
            int R = c >> 2, kc = (c & 3) ^ ((R >> 1) & 3);
            gload16(gA + (size_t)R * lda + t * 64 + ks * 32 + kc * 8,
                    dst + (j * 512 + wave * 64) * 8);
        }
    };
    auto stageB = [&](int t, int ks) {
        bf16* dst = smem + (t % 3) * BUFE + ATOT + ks * HALFB;
        int R = tid >> 2, kc = (tid & 3) ^ ((R >> 1) & 3);
        gload16(gB + (size_t)R * ldb + t * 64 + ks * 32 + kc * 8, dst + (wave * 64) * 8);
    };

    s16x8 afr[4], bfr[4];
    auto ldA = [&](int rb, int mh) {
#pragma unroll
        for (int m = 0; m < 4; ++m) {
            int R = wm * 128 + mh * 64 + m * 16 + r;
            afr[m] = *(const s16x8*)&smem[rb * BUFE + ksw * HALFA + R * 32 +
                                          ((kg ^ ((R >> 1) & 3)) * 8)];
        }
    };
    auto ldB = [&](int rb) {
#pragma unroll
        for (int n = 0; n < 4; ++n) {
            int R = wn * 64 + n * 16 + r;
            bfr[n] = *(const s16x8*)&smem[rb * BUFE + ATOT + ksw * HALFB + R * 32 +
                                          ((kg ^ ((R >> 1) & 3)) * 8)];
        }
    };
    auto preMFMA = [&]() {
        __builtin_amdgcn_s_barrier();
        asm volatile("s_waitcnt lgkmcnt(0)" ::: "memory");
        __builtin_amdgcn_sched_barrier(0);
        __builtin_amdgcn_s_setprio(1);
    };

    // prologue: stage tiles 0,1 (6 insts each)
    stageA(0, 0); stageB(0, 0); stageA(0, 1); stageB(0, 1);
    stageA(1, 0); stageB(1, 0); stageA(1, 1); stageB(1, 1);
    wait_vmcnt<6>();                        // tile 0 resident; tile 1 in flight
    __builtin_amdgcn_s_barrier();

    for (int t = 0; t < NT; ++t) {
        const int rb = t % 3;
        const bool gg = (t + 2 < NT);
        // ph0: B + A(mh0) reads; stage half of t+2 -> buf (t+2)%3 (never == rb)
        ldB(rb); ldA(rb, 0);
        if (gg) { stageA(t + 2, 0); stageB(t + 2, 0); }
        preMFMA();
#pragma unroll
        for (int m = 0; m < 4; ++m)
#pragma unroll
            for (int n = 0; n < 4; ++n)
                acc[m][n] = __builtin_amdgcn_mfma_f32_16x16x32_bf16(afr[m], bfr[n], acc[m][n], 0, 0, 0);
        __builtin_amdgcn_s_setprio(0);
        __builtin_amdgcn_s_barrier();
        // ph1: A(mh1) reads; stage other half of t+2
        ldA(rb, 1);
        if (gg) { stageA(t + 2, 1); stageB(t + 2, 1); }
        preMFMA();
#pragma unroll
        for (int m = 0; m < 4; ++m)
#pragma unroll
            for (int n = 0; n < 4; ++n)
                acc[4 + m][n] = __builtin_amdgcn_mfma_f32_16x16x32_bf16(afr[m], bfr[n], acc[4 + m][n], 0, 0, 0);
        __builtin_amdgcn_s_setprio(0);
        if (t + 1 < NT) {
            if (gg) wait_vmcnt<6>();        // tile t+1 resident (counted, never 0)
            else    wait_vmcnt<0>();
            __builtin_amdgcn_s_barrier();
        }
    }

    // ---- cross-ksw reduce via LDS, then fp32 RMW into out
    __syncthreads();                         // ring buffers dead
    float* red = (float*)smem;
    const int zone = (wm * 2 + wn) * 8192;   // 128x64 fp32 per (wm,wn)
    if (ksw == 1) {
#pragma unroll
        for (int mf = 0; mf < 8; ++mf) {
#pragma unroll
            for (int n = 0; n < 4; ++n) {
                int rl = (mf >> 2) * 64 + (mf & 3) * 16 + kg * 4;
                int cl = n * 16 + r;
#pragma unroll
                for (int j = 0; j < 4; ++j)
                    red[zone + (rl + j) * 64 + cl] = acc[mf][n][j];
            }
        }
    }
    __syncthreads();
    if (ksw == 0) {
        const size_t row0 = (size_t)tm * 256 + wm * 128;
        const int col0 = tn * 128 + wn * 64;
#pragma unroll
        for (int mf = 0; mf < 8; ++mf) {
#pragma unroll
            for (int j = 0; j < 4; ++j) {
                int rl = (mf >> 2) * 64 + (mf & 3) * 16 + kg * 4 + j;
                size_t rr = row0 + rl;
#pragma unroll
                for (int n = 0; n < 4; ++n) {
                    int cl = n * 16 + r;
                    float v = acc[mf][n][j] + red[zone + rl * 64 + cl];
                    O[rr * (size_t)ldc + col0 + cl] += v;
                }
            }
        }
    }
}

// ---------------------------------------------------------------- launch
extern "C" void kernel_launch(void* const* d_in, const int* in_sizes, int n_in,
                              void* d_out, int out_size, void* d_ws, size_t ws_size,
                              hipStream_t stream) {
    const float* x  = (const float*)d_in[0];
    const float* Wg = (const float*)d_in[1];
    const float* bg = (const float*)d_in[2];
    const float* W1 = (const float*)d_in[3];
    const float* b1 = (const float*)d_in[4];
    const float* W2 = (const float*)d_in[5];
    const float* b2 = (const float*)d_in[6];
    float* out = (float*)d_out;

    char* ws = (char*)d_ws;
    bf16* xb   = (bf16*)(ws);                          // 16 MiB  [N][D]
    bf16* W1Te = (bf16*)(ws + (16ull << 20));          // 8 MiB   [H][D] (one expert)
    bf16* W2P  = (bf16*)(ws + (24ull << 20));          // 16 MiB  [D][KPAIR] (pair)
    bf16* Hs   = (bf16*)(ws + (40ull << 20));          // 128 MiB [N][KPAIR] (pair)
    float* wts = (float*)(ws + (168ull << 20));        // 256 KiB [N][E]

    cvt_x_kernel<<<NROW * DDIM / 4 / 256, 256, 0, stream>>>(x, xb, NROW * DDIM / 4);
    gate_kernel<<<NROW / 4, 256, 0, stream>>>(x, Wg, bg, wts);
    out_init_kernel<<<NROW * DDIM / 256, 256, 0, stream>>>(wts, b2, out);

    for (int p = 0; p < 4; ++p) {
        for (int h = 0; h < 2; ++h) {
            int e = 2 * p + h;
            // W1[e]: [D][H] -> W1Te [H][D]
            transpose_cvt_kernel<<<dim3(HDIM / 32, DDIM / 32), 256, 0, stream>>>(
                W1 + (size_t)e * DDIM * HDIM, W1Te, DDIM, HDIM, DDIM);
            // GEMM1: Hs[:, h*H .. ] = w * relu(x @ W1[e] + b1[e])
            gemm1<<<512, 512, 0, stream>>>(
                xb, W1Te, Hs + (size_t)h * HDIM, b1 + (size_t)e * HDIM, wts,
                DDIM, DDIM, KPAIR, DDIM / 64, 32, 16, 2, e);
            // W2[e]: [H][D] -> W2P[:, h*H .. ] ([D][KPAIR])
            transpose_cvt_kernel<<<dim3(DDIM / 32, HDIM / 32), 256, 0, stream>>>(
                W2 + (size_t)e * HDIM * DDIM, W2P + (size_t)h * HDIM, HDIM, DDIM, KPAIR);
        }
        // GEMM2 pair: out += Hs @ W2P^T   (M=8192, N=1024, K=8192)
        gemm2pair<<<256, 512, 0, stream>>>(
            Hs, W2P, out, KPAIR, KPAIR, DDIM, KPAIR / 64, 32, 8, 1);
    }
}